// Round 1
// baseline (247.322 us; speedup 1.0000x reference)
//
#include <hip/hip_runtime.h>

// Overlap-add, gather formulation.
// Geometry fixed by setup_inputs(): B=32, NF=4000, FS=320, shift=160.
// sig_length = (NF-1)*shift + FS = 640160.
// Output sample t is covered by frames f with t - f*shift in [0, FS):
//   f = q = t/shift (offset r = t%shift)   if q <= NF-1
//   f = q-1         (offset r + shift)     if q >= 1
// Overlap count = 2 in the interior, 1 for t < shift and t >= NF*shift.

constexpr int B      = 32;
constexpr int NF     = 4000;
constexpr int FS     = 320;
constexpr int SHIFT  = 160;
constexpr int SIG_LEN     = (NF - 1) * SHIFT + FS;  // 640160
constexpr int GROUPS_PER_B = SIG_LEN / 4;           // 160040 float4 groups per batch

__global__ __launch_bounds__(256)
void ola_gather_kernel(const float* __restrict__ in, float* __restrict__ out) {
    const long long idx = (long long)blockIdx.x * blockDim.x + threadIdx.x;
    constexpr long long total = (long long)B * GROUPS_PER_B;
    if (idx >= total) return;

    const int b = (int)(idx / GROUPS_PER_B);
    const int g = (int)(idx % GROUPS_PER_B);
    const int t = g * 4;                 // first of 4 consecutive output samples
    const int q = t / SHIFT;             // candidate frame index (0..NF)
    const int r = t - q * SHIFT;         // offset within frame q, 4-aligned

    const float* __restrict__ inb = in + (long long)b * ((long long)NF * FS);

    float4 acc = make_float4(0.f, 0.f, 0.f, 0.f);
    int cnt = 0;

    // Frame q, offset r  (valid unless t is in the trailing half-window)
    if (q < NF) {
        const float4 v = *(const float4*)(inb + (long long)q * FS + r);
        acc.x += v.x; acc.y += v.y; acc.z += v.z; acc.w += v.w;
        ++cnt;
    }
    // Frame q-1, offset r+SHIFT  (valid unless t is in the leading half-window)
    if (q >= 1) {
        const float4 v = *(const float4*)(inb + (long long)(q - 1) * FS + r + SHIFT);
        acc.x += v.x; acc.y += v.y; acc.z += v.z; acc.w += v.w;
        ++cnt;
    }

    const float s = (cnt == 2) ? 0.5f : 1.0f;   // divide by overlap count
    float4 o;
    o.x = acc.x * s; o.y = acc.y * s; o.z = acc.z * s; o.w = acc.w * s;
    *(float4*)(out + (long long)b * SIG_LEN + t) = o;
}

extern "C" void kernel_launch(void* const* d_in, const int* in_sizes, int n_in,
                              void* d_out, int out_size, void* d_ws, size_t ws_size,
                              hipStream_t stream) {
    const float* in = (const float*)d_in[0];
    float* out = (float*)d_out;

    constexpr long long total  = (long long)B * GROUPS_PER_B;  // 5,121,280 threads
    constexpr int       block  = 256;
    const int           blocks = (int)((total + block - 1) / block);  // 20005

    ola_gather_kernel<<<blocks, block, 0, stream>>>(in, out);
}